// Round 1
// baseline (490.872 us; speedup 1.0000x reference)
//
#include <hip/hip_runtime.h>
#include <hip/hip_bf16.h>
#include <cstdint>

#define B_ 2
#define S_ 2048
#define E_ 2048
#define H_ 16
#define KV_ 4
#define HD_ 128
#define BS_ (B_*S_)
#define QKV_LD 3072
#define SM_SCALE 0.08838834764831845f   // 1/sqrt(128)

typedef __attribute__((ext_vector_type(8))) __bf16 bf16x8;
typedef __attribute__((ext_vector_type(4))) float  floatx4;

__device__ __forceinline__ unsigned short f2bf(float f) {
  union { float f; unsigned u; } v; v.f = f;
  unsigned r = v.u + 0x7fffu + ((v.u >> 16) & 1u);   // RTNE
  return (unsigned short)(r >> 16);
}
__device__ __forceinline__ float bf2f(unsigned short u) {
  union { unsigned u; float f; } v; v.u = ((unsigned)u) << 16; return v.f;
}

// ---------------- fp32 -> bf16 convert (with column offset into dst) ----------
__global__ __launch_bounds__(256)
void cvt_bf16(const float* __restrict__ src, unsigned short* __restrict__ dst,
              int rows, int cols, int dld, int doff) {
  int idx = blockIdx.x * 256 + threadIdx.x;
  int n = rows * cols / 4;
  if (idx >= n) return;
  int e = idx * 4;
  int r = e / cols, c = e % cols;
  float4 v = *(const float4*)(src + (size_t)r * cols + c);
  ushort4 o;
  o.x = f2bf(v.x); o.y = f2bf(v.y); o.z = f2bf(v.z); o.w = f2bf(v.w);
  *(ushort4*)(dst + (size_t)r * dld + doff + c) = o;
}

// ---------------- RoPE on q (cols 0..2047) and k (cols 2048..2559) ------------
__global__ __launch_bounds__(256)
void rope_kernel(unsigned short* __restrict__ qkv) {
  const int PPR = 1280;  // 1024 q pairs + 256 k pairs per row
  int idx = blockIdx.x * 256 + threadIdx.x;
  if (idx >= BS_ * PPR) return;
  int row = idx / PPR, p = idx - row * PPR;
  int col = (p < 1024) ? (2 * p) : (2048 + 2 * (p - 1024));
  int d = p & 63;
  int s = row & (S_ - 1);
  float freq = expf(-(float)d * 0.14391156831212787f);  // ln(10000)/64
  float ang = (float)s * freq;
  float c = cosf(ang), sn = sinf(ang);
  unsigned short* ptr = qkv + (size_t)row * QKV_LD + col;
  float x1 = bf2f(ptr[0]), x2 = bf2f(ptr[1]);
  ptr[0] = f2bf(x1 * c - x2 * sn);
  ptr[1] = f2bf(x1 * sn + x2 * c);
}

// ---------------- bf16 GEMM: C[M][N] = A[M][K] * B[K][N] ----------------------
// BM=BN=128, BK=32; 256 threads = 4 waves in 2x2; each wave 64x64 (4x4 MFMA tiles)
template<bool OUT_BF16>
__global__ __launch_bounds__(256, 2)
void gemm_bf16(const unsigned short* __restrict__ A,
               const unsigned short* __restrict__ Bm,
               void* __restrict__ C, int M, int N, int K) {
  constexpr int ST = 72;  // halfword stride: 144B rows -> b128-aligned, 2-way banks
  __shared__ unsigned short Ash[128 * ST];
  __shared__ unsigned short Bt[128 * ST];   // Bt[n][k]
  const int tid = threadIdx.x;
  const int lane = tid & 63;
  const int l16 = lane & 15, l4 = lane >> 4;
  const int wave = tid >> 6;
  const int wm = (wave >> 1) * 64, wn = (wave & 1) * 64;
  const int bm = blockIdx.y * 128, bn = blockIdx.x * 128;

  floatx4 acc[4][4] = {};

  for (int kb = 0; kb < K; kb += 32) {
    __syncthreads();
    // stage A: 128 rows x 32 k, row-major, vectorized
#pragma unroll
    for (int i = 0; i < 2; ++i) {
      int chunk = tid + i * 256;           // 0..511
      int r = chunk >> 2, cc = (chunk & 3) * 8;
      uint4 v = *(const uint4*)(A + (size_t)(bm + r) * K + kb + cc);
      *(uint4*)(Ash + r * ST + cc) = v;
    }
    // stage B transposed: column-gather (coalesced per-j across lanes), b128 LDS write
#pragma unroll
    for (int i = 0; i < 2; ++i) {
      int chunk = tid + i * 256;           // 0..511
      int col = chunk & 127, kg = (chunk >> 7) * 8;
      const unsigned short* bp = Bm + (size_t)(kb + kg) * N + bn + col;
      union { unsigned short u[8]; uint4 v; } t;
#pragma unroll
      for (int j = 0; j < 8; ++j) t.u[j] = bp[(size_t)j * N];
      *(uint4*)(Bt + col * ST + kg) = t.v;
    }
    __syncthreads();
    bf16x8 af[4], bf[4];
#pragma unroll
    for (int t = 0; t < 4; ++t)
      af[t] = *(const bf16x8*)(Ash + (wm + t * 16 + l16) * ST + l4 * 8);
#pragma unroll
    for (int t = 0; t < 4; ++t)
      bf[t] = *(const bf16x8*)(Bt + (wn + t * 16 + l16) * ST + l4 * 8);
#pragma unroll
    for (int tm = 0; tm < 4; ++tm)
#pragma unroll
      for (int tn = 0; tn < 4; ++tn)
        acc[tm][tn] = __builtin_amdgcn_mfma_f32_16x16x32_bf16(af[tm], bf[tn], acc[tm][tn], 0, 0, 0);
  }
  // epilogue: D layout col=lane&15, row=(lane>>4)*4+reg
#pragma unroll
  for (int tm = 0; tm < 4; ++tm)
#pragma unroll
    for (int tn = 0; tn < 4; ++tn)
#pragma unroll
      for (int r = 0; r < 4; ++r) {
        int row = bm + wm + tm * 16 + l4 * 4 + r;
        int col = bn + wn + tn * 16 + l16;
        float v = acc[tm][tn][r];
        if (OUT_BF16) ((unsigned short*)C)[(size_t)row * N + col] = f2bf(v);
        else          ((float*)C)[(size_t)row * N + col] = v;
      }
}

// ---------------- flash attention (causal, GQA) -------------------------------
// grid (S/64, B*H); block 256 = 4 waves; wave w: q rows q0+w*16 .. +15
__global__ __launch_bounds__(256, 2)
void gqa_attention(const unsigned short* __restrict__ qkv,
                   unsigned short* __restrict__ out) {
  constexpr int KST = 136;  // 272B rows: aligned, 2-way banks
  constexpr int VST = 72;   // Vt[hd][krow]
  constexpr int PST = 72;   // P[m][k]
  __shared__ unsigned short Ksh[32 * KST];
  __shared__ unsigned short Vt[128 * VST];
  __shared__ unsigned short Psh[4][16 * PST];

  const int tid = threadIdx.x, lane = tid & 63, wave = tid >> 6;
  const int l16 = lane & 15, l4 = lane >> 4;
  const int bh = blockIdx.y, b = bh >> 4, h = bh & 15, kvh = h >> 2;
  const int q0 = blockIdx.x * 64;
  const int qrow = q0 + wave * 16;

  // Q fragments (A layout: m=lane&15, k=quad*8+j), 4 chunks of K=32 over HD=128
  bf16x8 qf[4];
  {
    const unsigned short* qp = qkv + (size_t)(b * S_ + qrow + l16) * QKV_LD + h * HD_;
#pragma unroll
    for (int c = 0; c < 4; ++c)
      qf[c] = *(const bf16x8*)(qp + c * 32 + l4 * 8);
  }

  floatx4 acc[8] = {};   // O accumulator: 8 hd-tiles of 16x16
  float mrow[4], lrow[4];
#pragma unroll
  for (int r = 0; r < 4; ++r) { mrow[r] = -3e38f; lrow[r] = 0.f; }

  const int kend = q0 + 64;
  for (int kb = 0; kb < kend; kb += 32) {
    __syncthreads();
    // stage K chunk: 32 rows x 128, row-major vectorized
#pragma unroll
    for (int i = 0; i < 2; ++i) {
      int chunk = tid + i * 256;
      int kr = chunk >> 4, cc = (chunk & 15) * 8;
      uint4 v = *(const uint4*)(qkv + (size_t)(b * S_ + kb + kr) * QKV_LD + 2048 + kvh * HD_ + cc);
      *(uint4*)(Ksh + kr * KST + cc) = v;
    }
    // stage V transposed: column-gather, b128 LDS write
#pragma unroll
    for (int i = 0; i < 2; ++i) {
      int chunk = tid + i * 256;
      int col = chunk & 127, kg = (chunk >> 7) * 8;
      const unsigned short* vp = qkv + (size_t)(b * S_ + kb + kg) * QKV_LD + 2560 + kvh * HD_ + col;
      union { unsigned short u[8]; uint4 v; } t;
#pragma unroll
      for (int j = 0; j < 8; ++j) t.u[j] = vp[(size_t)j * QKV_LD];
      *(uint4*)(Vt + col * VST + kg) = t.v;
    }
    __syncthreads();

    const bool active = kb < qrow + 16;  // skip fully-masked chunks for this wave
    if (active) {
      // S = Q K^T : two 16x16 tiles (k cols kb..+15, kb+16..+31)
      floatx4 sacc[2] = {};
#pragma unroll
      for (int half = 0; half < 2; ++half)
#pragma unroll
        for (int c = 0; c < 4; ++c) {
          bf16x8 kf = *(const bf16x8*)(Ksh + (half * 16 + l16) * KST + c * 32 + l4 * 8);
          sacc[half] = __builtin_amdgcn_mfma_f32_16x16x32_bf16(qf[c], kf, sacc[half], 0, 0, 0);
        }
      // scale + causal mask
      float s[2][4];
#pragma unroll
      for (int half = 0; half < 2; ++half)
#pragma unroll
        for (int r = 0; r < 4; ++r) {
          float v = sacc[half][r] * SM_SCALE;
          int ka = kb + half * 16 + l16;
          int qa = qrow + l4 * 4 + r;
          s[half][r] = (ka > qa) ? -3e38f : v;
        }
      // row max across the 16 cols (lanes sharing l4-group)
      float mx[4];
#pragma unroll
      for (int r = 0; r < 4; ++r) mx[r] = fmaxf(s[0][r], s[1][r]);
#pragma unroll
      for (int off = 1; off < 16; off <<= 1)
#pragma unroll
        for (int r = 0; r < 4; ++r)
          mx[r] = fmaxf(mx[r], __shfl_xor(mx[r], off, 64));
      float mnew[4], alpha[4], ps[4];
#pragma unroll
      for (int r = 0; r < 4; ++r) {
        mnew[r] = fmaxf(mrow[r], mx[r]);
        alpha[r] = __expf(mrow[r] - mnew[r]);
        ps[r] = 0.f;
      }
#pragma unroll
      for (int t = 0; t < 8; ++t)
#pragma unroll
        for (int r = 0; r < 4; ++r)
          acc[t][r] *= alpha[r];
      // P = exp(s - mnew), write to LDS in A layout
#pragma unroll
      for (int half = 0; half < 2; ++half)
#pragma unroll
        for (int r = 0; r < 4; ++r) {
          float p = __expf(s[half][r] - mnew[r]);
          ps[r] += p;
          Psh[wave][(l4 * 4 + r) * PST + half * 16 + l16] = f2bf(p);
        }
#pragma unroll
      for (int off = 1; off < 16; off <<= 1)
#pragma unroll
        for (int r = 0; r < 4; ++r)
          ps[r] += __shfl_xor(ps[r], off, 64);
#pragma unroll
      for (int r = 0; r < 4; ++r) {
        lrow[r] = lrow[r] * alpha[r] + ps[r];
        mrow[r] = mnew[r];
      }
    }
    __syncthreads();  // P write -> P read ordering (and uniform barrier)
    if (active) {
      bf16x8 pf = *(const bf16x8*)(&Psh[wave][l16 * PST + l4 * 8]);
#pragma unroll
      for (int t = 0; t < 8; ++t) {
        bf16x8 vf = *(const bf16x8*)(Vt + (t * 16 + l16) * VST + l4 * 8);
        acc[t] = __builtin_amdgcn_mfma_f32_16x16x32_bf16(pf, vf, acc[t], 0, 0, 0);
      }
    }
  }
  // epilogue: out[b*S + q][h*128 + hd] = acc / l
  float inv[4];
#pragma unroll
  for (int r = 0; r < 4; ++r) inv[r] = 1.0f / lrow[r];
#pragma unroll
  for (int t = 0; t < 8; ++t)
#pragma unroll
    for (int r = 0; r < 4; ++r) {
      int row = b * S_ + qrow + l4 * 4 + r;
      int col = h * HD_ + t * 16 + l16;
      out[(size_t)row * 2048 + col] = f2bf(acc[t][r] * inv[r]);
    }
}

// ---------------- launcher ----------------------------------------------------
extern "C" void kernel_launch(void* const* d_in, const int* in_sizes, int n_in,
                              void* d_out, int out_size, void* d_ws, size_t ws_size,
                              hipStream_t stream) {
  const float* x  = (const float*)d_in[0];
  const float* Wq = (const float*)d_in[1];
  const float* Wk = (const float*)d_in[2];
  const float* Wv = (const float*)d_in[3];
  const float* Wo = (const float*)d_in[4];
  float* out = (float*)d_out;

  char* ws = (char*)d_ws;
  unsigned short* xb   = (unsigned short*)(ws);                       // 16 MB
  unsigned short* wqkv = (unsigned short*)(ws + 16777216);            // 12 MB
  unsigned short* wo   = (unsigned short*)(ws + 29360128);            // 8 MB
  unsigned short* qkv  = (unsigned short*)(ws + 37748736);            // 24 MB
  unsigned short* attn = (unsigned short*)(ws + 62914560);            // 16 MB

  // converts
  {
    int n = 4096 * 2048 / 4;
    cvt_bf16<<<(n + 255) / 256, 256, 0, stream>>>(x, xb, 4096, 2048, 2048, 0);
  }
  {
    int n = 2048 * 2048 / 4;
    cvt_bf16<<<(n + 255) / 256, 256, 0, stream>>>(Wq, wqkv, 2048, 2048, 3072, 0);
  }
  {
    int n = 2048 * 512 / 4;
    cvt_bf16<<<(n + 255) / 256, 256, 0, stream>>>(Wk, wqkv, 2048, 512, 3072, 2048);
    cvt_bf16<<<(n + 255) / 256, 256, 0, stream>>>(Wv, wqkv, 2048, 512, 3072, 2560);
  }
  {
    int n = 2048 * 2048 / 4;
    cvt_bf16<<<(n + 255) / 256, 256, 0, stream>>>(Wo, wo, 2048, 2048, 2048, 0);
  }

  // qkv = x @ [Wq|Wk|Wv]
  gemm_bf16<true><<<dim3(3072 / 128, 4096 / 128), 256, 0, stream>>>(xb, wqkv, qkv, 4096, 3072, 2048);
  // RoPE in place on q,k
  rope_kernel<<<(4096 * 1280 + 255) / 256, 256, 0, stream>>>(qkv);
  // flash attention
  gqa_attention<<<dim3(S_ / 64, B_ * H_), 256, 0, stream>>>(qkv, attn);
  // out = attn @ Wo
  gemm_bf16<false><<<dim3(2048 / 128, 4096 / 128), 256, 0, stream>>>(attn, wo, out, 4096, 2048, 2048);
}

// Round 2
// 410.003 us; speedup vs baseline: 1.1972x; 1.1972x over previous
//
#include <hip/hip_runtime.h>
#include <hip/hip_bf16.h>
#include <cstdint>

#define B_ 2
#define S_ 2048
#define E_ 2048
#define H_ 16
#define KV_ 4
#define HD_ 128
#define BS_ (B_*S_)
#define QKV_LD 3072
#define SM_SCALE 0.08838834764831845f   // 1/sqrt(128)

typedef __attribute__((ext_vector_type(8))) __bf16 bf16x8;
typedef __attribute__((ext_vector_type(4))) float  floatx4;

__device__ __forceinline__ unsigned short f2bf(float f) {
  union { float f; unsigned u; } v; v.f = f;
  unsigned r = v.u + 0x7fffu + ((v.u >> 16) & 1u);   // RTNE
  return (unsigned short)(r >> 16);
}
__device__ __forceinline__ float bf2f(unsigned short u) {
  union { unsigned u; float f; } v; v.u = ((unsigned)u) << 16; return v.f;
}

// ---------------- fp32 -> bf16 convert (with column offset into dst) ----------
__global__ __launch_bounds__(256)
void cvt_bf16(const float* __restrict__ src, unsigned short* __restrict__ dst,
              int rows, int cols, int dld, int doff) {
  int idx = blockIdx.x * 256 + threadIdx.x;
  int n = rows * cols / 4;
  if (idx >= n) return;
  int e = idx * 4;
  int r = e / cols, c = e % cols;
  float4 v = *(const float4*)(src + (size_t)r * cols + c);
  ushort4 o;
  o.x = f2bf(v.x); o.y = f2bf(v.y); o.z = f2bf(v.z); o.w = f2bf(v.w);
  *(ushort4*)(dst + (size_t)r * dld + doff + c) = o;
}

// ---------------- RoPE on q (cols 0..2047) and k (cols 2048..2559) ------------
__global__ __launch_bounds__(256)
void rope_kernel(unsigned short* __restrict__ qkv) {
  const int PPR = 1280;  // 1024 q pairs + 256 k pairs per row
  int idx = blockIdx.x * 256 + threadIdx.x;
  if (idx >= BS_ * PPR) return;
  int row = idx / PPR, p = idx - row * PPR;
  int col = (p < 1024) ? (2 * p) : (2048 + 2 * (p - 1024));
  int d = p & 63;
  int s = row & (S_ - 1);
  float freq = expf(-(float)d * 0.14391156831212787f);  // ln(10000)/64
  float ang = (float)s * freq;
  float c = cosf(ang), sn = sinf(ang);
  unsigned short* ptr = qkv + (size_t)row * QKV_LD + col;
  float x1 = bf2f(ptr[0]), x2 = bf2f(ptr[1]);
  ptr[0] = f2bf(x1 * c - x2 * sn);
  ptr[1] = f2bf(x1 * sn + x2 * c);
}

// ---------------- V transpose: qkv V-cols -> vt[g][hd][s] ---------------------
// grid (32, 16): x = s-tile (64), y = g*2 + hh-half; block 256
__global__ __launch_bounds__(256)
void vtrans_kernel(const unsigned short* __restrict__ qkv,
                   unsigned short* __restrict__ vt) {
  __shared__ unsigned short tile[64 * 72];
  const int tid = threadIdx.x;
  const int s0 = blockIdx.x * 64;
  const int g = blockIdx.y >> 1;          // b*4 + kvh
  const int hh = (blockIdx.y & 1) * 64;
  const int b = g >> 2, kvh = g & 3;
#pragma unroll
  for (int i = 0; i < 2; ++i) {
    int chunk = tid + i * 256;
    int r = chunk >> 3, c = (chunk & 7) * 8;
    uint4 v = *(const uint4*)(qkv + (size_t)(b * S_ + s0 + r) * QKV_LD + 2560 + kvh * HD_ + hh + c);
    *(uint4*)(tile + r * 72 + c) = v;
  }
  __syncthreads();
#pragma unroll
  for (int i = 0; i < 2; ++i) {
    int chunk = tid + i * 256;
    int hdr = chunk >> 3, sc = (chunk & 7) * 8;
    union { unsigned short u[8]; uint4 v; } t;
#pragma unroll
    for (int j = 0; j < 8; ++j) t.u[j] = tile[(sc + j) * 72 + hdr];
    *(uint4*)(vt + (size_t)(g * HD_ + hh + hdr) * S_ + s0 + sc) = t.v;
  }
}

// ---------------- bf16 GEMM: C[M][N] = A[M][K] * B[K][N] ----------------------
template<bool OUT_BF16>
__global__ __launch_bounds__(256, 2)
void gemm_bf16(const unsigned short* __restrict__ A,
               const unsigned short* __restrict__ Bm,
               void* __restrict__ C, int M, int N, int K) {
  constexpr int ST = 72;
  __shared__ unsigned short Ash[128 * ST];
  __shared__ unsigned short Bt[128 * ST];   // Bt[n][k]
  const int tid = threadIdx.x;
  const int lane = tid & 63;
  const int l16 = lane & 15, l4 = lane >> 4;
  const int wave = tid >> 6;
  const int wm = (wave >> 1) * 64, wn = (wave & 1) * 64;
  const int bm = blockIdx.y * 128, bn = blockIdx.x * 128;

  floatx4 acc[4][4] = {};

  for (int kb = 0; kb < K; kb += 32) {
    __syncthreads();
#pragma unroll
    for (int i = 0; i < 2; ++i) {
      int chunk = tid + i * 256;
      int r = chunk >> 2, cc = (chunk & 3) * 8;
      uint4 v = *(const uint4*)(A + (size_t)(bm + r) * K + kb + cc);
      *(uint4*)(Ash + r * ST + cc) = v;
    }
#pragma unroll
    for (int i = 0; i < 2; ++i) {
      int chunk = tid + i * 256;
      int col = chunk & 127, kg = (chunk >> 7) * 8;
      const unsigned short* bp = Bm + (size_t)(kb + kg) * N + bn + col;
      union { unsigned short u[8]; uint4 v; } t;
#pragma unroll
      for (int j = 0; j < 8; ++j) t.u[j] = bp[(size_t)j * N];
      *(uint4*)(Bt + col * ST + kg) = t.v;
    }
    __syncthreads();
    bf16x8 af[4], bf[4];
#pragma unroll
    for (int t = 0; t < 4; ++t)
      af[t] = *(const bf16x8*)(Ash + (wm + t * 16 + l16) * ST + l4 * 8);
#pragma unroll
    for (int t = 0; t < 4; ++t)
      bf[t] = *(const bf16x8*)(Bt + (wn + t * 16 + l16) * ST + l4 * 8);
#pragma unroll
    for (int tm = 0; tm < 4; ++tm)
#pragma unroll
      for (int tn = 0; tn < 4; ++tn)
        acc[tm][tn] = __builtin_amdgcn_mfma_f32_16x16x32_bf16(af[tm], bf[tn], acc[tm][tn], 0, 0, 0);
  }
#pragma unroll
  for (int tm = 0; tm < 4; ++tm)
#pragma unroll
    for (int tn = 0; tn < 4; ++tn)
#pragma unroll
      for (int r = 0; r < 4; ++r) {
        int row = bm + wm + tm * 16 + l4 * 4 + r;
        int col = bn + wn + tn * 16 + l16;
        float v = acc[tm][tn][r];
        if (OUT_BF16) ((unsigned short*)C)[(size_t)row * N + col] = f2bf(v);
        else          ((float*)C)[(size_t)row * N + col] = v;
      }
}

// ---------------- flash attention v2 (causal, GQA, head-parallel waves) -------
// grid (32, 8): x = balanced q-pair index, y = g = b*4+kvh
// block 512 = 8 waves: wave w -> head kvh*4 + (w&3), q-subtile (w>>2)
// phase 0: q0 = bx*32 ; phase 1: q0 = 2016 - bx*32  (total work constant)
__global__ __launch_bounds__(512, 2)
void gqa_attention(const unsigned short* __restrict__ qkv,
                   const unsigned short* __restrict__ vt,
                   unsigned short* __restrict__ out) {
  constexpr int KST = 136;  // K rows (32 x 128), padded
  constexpr int VST = 40;   // Vt rows: [hd][k] (128 x 32), padded
  constexpr int PST = 40;   // P per wave: [16][32], padded
  __shared__ unsigned short Ksh[32 * KST];   // 8704 B
  __shared__ unsigned short Vtsh[128 * VST]; // 10240 B
  __shared__ unsigned short Psh[8][16 * PST];// 10240 B

  const int tid = threadIdx.x, lane = tid & 63, wave = tid >> 6;
  const int l16 = lane & 15, l4 = lane >> 4;
  const int g = blockIdx.y, b = g >> 2, kvh = g & 3;
  const int h = kvh * 4 + (wave & 3);
  const int qsub = wave >> 2;
  const int bx = blockIdx.x;

  // staging indices (512 threads)
  const int kr = tid >> 4, kc = (tid & 15) * 8;   // K: 32 rows x 128 cols
  const int vr = tid >> 2, vc = (tid & 3) * 8;    // Vt: 128 rows x 32 cols

  for (int phase = 0; phase < 2; ++phase) {
    const int q0 = phase ? (S_ - 32 - bx * 32) : (bx * 32);
    const int qt = q0 + qsub * 16;

    // Q fragments (A layout): 4 chunks of K=32 over HD=128
    bf16x8 qf[4];
    {
      const unsigned short* qp = qkv + (size_t)(b * S_ + qt + l16) * QKV_LD + h * HD_;
#pragma unroll
      for (int c = 0; c < 4; ++c)
        qf[c] = *(const bf16x8*)(qp + c * 32 + l4 * 8);
    }

    floatx4 acc[8] = {};
    float mrow[4], lrow[4];
#pragma unroll
    for (int r = 0; r < 4; ++r) { mrow[r] = -3e38f; lrow[r] = 0.f; }

    for (int kb = 0; kb <= q0; kb += 32) {
      __syncthreads();
      // stage K chunk (row-major, coalesced uint4)
      {
        uint4 v = *(const uint4*)(qkv + (size_t)(b * S_ + kb + kr) * QKV_LD + 2048 + kvh * HD_ + kc);
        *(uint4*)(Ksh + kr * KST + kc) = v;
      }
      // stage Vt chunk (pre-transposed, coalesced uint4)
      {
        uint4 v = *(const uint4*)(vt + (size_t)(g * HD_ + vr) * S_ + kb + vc);
        *(uint4*)(Vtsh + vr * VST + vc) = v;
      }
      __syncthreads();

      // S = Q K^T : two 16x16 k-tiles
      floatx4 sacc[2] = {};
#pragma unroll
      for (int half = 0; half < 2; ++half)
#pragma unroll
        for (int c = 0; c < 4; ++c) {
          bf16x8 kf = *(const bf16x8*)(Ksh + (half * 16 + l16) * KST + c * 32 + l4 * 8);
          sacc[half] = __builtin_amdgcn_mfma_f32_16x16x32_bf16(qf[c], kf, sacc[half], 0, 0, 0);
        }
      float s[2][4];
      if (kb == q0) {  // wave-uniform: only the diagonal chunk needs masking
#pragma unroll
        for (int half = 0; half < 2; ++half)
#pragma unroll
          for (int r = 0; r < 4; ++r) {
            int ka = kb + half * 16 + l16;
            int qa = qt + l4 * 4 + r;
            s[half][r] = (ka > qa) ? -3e38f : sacc[half][r] * SM_SCALE;
          }
      } else {
#pragma unroll
        for (int half = 0; half < 2; ++half)
#pragma unroll
          for (int r = 0; r < 4; ++r)
            s[half][r] = sacc[half][r] * SM_SCALE;
      }
      // online softmax: row reductions across 16 lanes
      float mx[4];
#pragma unroll
      for (int r = 0; r < 4; ++r) mx[r] = fmaxf(s[0][r], s[1][r]);
#pragma unroll
      for (int off = 1; off < 16; off <<= 1)
#pragma unroll
        for (int r = 0; r < 4; ++r)
          mx[r] = fmaxf(mx[r], __shfl_xor(mx[r], off, 64));
      float mnew[4], alpha[4], ps[4];
#pragma unroll
      for (int r = 0; r < 4; ++r) {
        mnew[r] = fmaxf(mrow[r], mx[r]);
        alpha[r] = __expf(mrow[r] - mnew[r]);
        ps[r] = 0.f;
      }
#pragma unroll
      for (int t = 0; t < 8; ++t)
#pragma unroll
        for (int r = 0; r < 4; ++r)
          acc[t][r] *= alpha[r];
#pragma unroll
      for (int half = 0; half < 2; ++half)
#pragma unroll
        for (int r = 0; r < 4; ++r) {
          float p = __expf(s[half][r] - mnew[r]);
          ps[r] += p;
          Psh[wave][(l4 * 4 + r) * PST + half * 16 + l16] = f2bf(p);
        }
#pragma unroll
      for (int off = 1; off < 16; off <<= 1)
#pragma unroll
        for (int r = 0; r < 4; ++r)
          ps[r] += __shfl_xor(ps[r], off, 64);
#pragma unroll
      for (int r = 0; r < 4; ++r) {
        lrow[r] = lrow[r] * alpha[r] + ps[r];
        mrow[r] = mnew[r];
      }
      // PV: P (16x32) @ V (32x128); in-wave LDS RAW (DS pipe is in-order per wave)
      bf16x8 pf = *(const bf16x8*)(&Psh[wave][l16 * PST + l4 * 8]);
#pragma unroll
      for (int t = 0; t < 8; ++t) {
        bf16x8 vf = *(const bf16x8*)(Vtsh + (t * 16 + l16) * VST + l4 * 8);
        acc[t] = __builtin_amdgcn_mfma_f32_16x16x32_bf16(pf, vf, acc[t], 0, 0, 0);
      }
    }
    // epilogue
    float inv[4];
#pragma unroll
    for (int r = 0; r < 4; ++r) inv[r] = 1.0f / lrow[r];
#pragma unroll
    for (int t = 0; t < 8; ++t)
#pragma unroll
      for (int r = 0; r < 4; ++r) {
        int row = b * S_ + qt + l4 * 4 + r;
        int col = h * HD_ + t * 16 + l16;
        out[(size_t)row * 2048 + col] = f2bf(acc[t][r] * inv[r]);
      }
    __syncthreads();  // phase boundary: all waves done before restaging
  }
}

// ---------------- launcher ----------------------------------------------------
extern "C" void kernel_launch(void* const* d_in, const int* in_sizes, int n_in,
                              void* d_out, int out_size, void* d_ws, size_t ws_size,
                              hipStream_t stream) {
  const float* x  = (const float*)d_in[0];
  const float* Wq = (const float*)d_in[1];
  const float* Wk = (const float*)d_in[2];
  const float* Wv = (const float*)d_in[3];
  const float* Wo = (const float*)d_in[4];
  float* out = (float*)d_out;

  char* ws = (char*)d_ws;
  unsigned short* xb   = (unsigned short*)(ws);                       // 16 MB (dead after GEMM1)
  unsigned short* wqkv = (unsigned short*)(ws + 16777216);            // 12 MB
  unsigned short* wo   = (unsigned short*)(ws + 29360128);            // 8 MB
  unsigned short* qkv  = (unsigned short*)(ws + 37748736);            // 24 MB
  unsigned short* attn = (unsigned short*)(ws + 62914560);            // 16 MB
  unsigned short* vt   = (unsigned short*)(ws);                       // 4 MB, aliases xb

  {
    int n = 4096 * 2048 / 4;
    cvt_bf16<<<(n + 255) / 256, 256, 0, stream>>>(x, xb, 4096, 2048, 2048, 0);
  }
  {
    int n = 2048 * 2048 / 4;
    cvt_bf16<<<(n + 255) / 256, 256, 0, stream>>>(Wq, wqkv, 2048, 2048, 3072, 0);
  }
  {
    int n = 2048 * 512 / 4;
    cvt_bf16<<<(n + 255) / 256, 256, 0, stream>>>(Wk, wqkv, 2048, 512, 3072, 2048);
    cvt_bf16<<<(n + 255) / 256, 256, 0, stream>>>(Wv, wqkv, 2048, 512, 3072, 2560);
  }
  {
    int n = 2048 * 2048 / 4;
    cvt_bf16<<<(n + 255) / 256, 256, 0, stream>>>(Wo, wo, 2048, 2048, 2048, 0);
  }

  // qkv = x @ [Wq|Wk|Wv]
  gemm_bf16<true><<<dim3(3072 / 128, 4096 / 128), 256, 0, stream>>>(xb, wqkv, qkv, 4096, 3072, 2048);
  // RoPE in place on q,k (xb now dead; vt aliases it)
  rope_kernel<<<(4096 * 1280 + 255) / 256, 256, 0, stream>>>(qkv);
  // V transpose into vt[g][hd][s]
  vtrans_kernel<<<dim3(32, 16), 256, 0, stream>>>(qkv, vt);
  // flash attention
  gqa_attention<<<dim3(32, 8), 512, 0, stream>>>(qkv, vt, attn);
  // out = attn @ Wo
  gemm_bf16<false><<<dim3(2048 / 128, 4096 / 128), 256, 0, stream>>>(attn, wo, out, 4096, 2048, 2048);
}

// Round 3
// 365.579 us; speedup vs baseline: 1.3427x; 1.1215x over previous
//
#include <hip/hip_runtime.h>
#include <hip/hip_bf16.h>
#include <cstdint>

#define B_ 2
#define S_ 2048
#define E_ 2048
#define H_ 16
#define KV_ 4
#define HD_ 128
#define BS_ (B_*S_)
#define QKV_LD 3072
#define SM_SCALE 0.08838834764831845f   // 1/sqrt(128)

typedef __attribute__((ext_vector_type(8))) __bf16 bf16x8;
typedef __attribute__((ext_vector_type(4))) float  floatx4;

__device__ __forceinline__ unsigned short f2bf(float f) {
  union { float f; unsigned u; } v; v.f = f;
  unsigned r = v.u + 0x7fffu + ((v.u >> 16) & 1u);   // RTNE
  return (unsigned short)(r >> 16);
}
__device__ __forceinline__ float bf2f(unsigned short u) {
  union { unsigned u; float f; } v; v.u = ((unsigned)u) << 16; return v.f;
}

__device__ __forceinline__ void async_cp16(const void* g, void* l) {
  __builtin_amdgcn_global_load_lds(
      (const __attribute__((address_space(1))) void*)g,
      (__attribute__((address_space(3))) void*)l, 16, 0, 0);
}

// ---------------- fp32 -> bf16 convert (plain) --------------------------------
__global__ __launch_bounds__(256)
void cvt_bf16(const float* __restrict__ src, unsigned short* __restrict__ dst,
              int n4) {
  int idx = blockIdx.x * 256 + threadIdx.x;
  if (idx >= n4) return;
  float4 v = *(const float4*)(src + (size_t)idx * 4);
  ushort4 o;
  o.x = f2bf(v.x); o.y = f2bf(v.y); o.z = f2bf(v.z); o.w = f2bf(v.w);
  *(ushort4*)(dst + (size_t)idx * 4) = o;
}

// ---------------- fp32 W[K][N] -> bf16 W^T[N][K] (transpose convert) ----------
// grid (N/64, K/64), block 256
__global__ __launch_bounds__(256)
void cvt_bf16_t(const float* __restrict__ src, unsigned short* __restrict__ dst,
                int N, int dld, int noff) {
  __shared__ float tile[64 * 65];
  const int t = threadIdx.x;
  const int bk = blockIdx.y * 64, bn = blockIdx.x * 64;
  const int r = t >> 2, cg = t & 3;
#pragma unroll
  for (int i = 0; i < 4; ++i) {
    int c = cg * 16 + i * 4;
    float4 v = *(const float4*)(src + (size_t)(bk + r) * N + bn + c);
    tile[r * 65 + c] = v.x; tile[r * 65 + c + 1] = v.y;
    tile[r * 65 + c + 2] = v.z; tile[r * 65 + c + 3] = v.w;
  }
  __syncthreads();
  const int nl = t >> 2, kg = t & 3;
  union { unsigned short u[16]; uint4 q[2]; } o;
#pragma unroll
  for (int j = 0; j < 16; ++j)
    o.u[j] = f2bf(tile[(kg * 16 + j) * 65 + nl]);
  unsigned short* dp = dst + (size_t)(noff + bn + nl) * dld + bk + kg * 16;
  *(uint4*)(dp) = o.q[0];
  *(uint4*)(dp + 8) = o.q[1];
}

// ---------------- RoPE on q (cols 0..2047) and k (cols 2048..2559) ------------
__global__ __launch_bounds__(256)
void rope_kernel(unsigned short* __restrict__ qkv) {
  const int PPR = 1280;  // 1024 q pairs + 256 k pairs per row
  int idx = blockIdx.x * 256 + threadIdx.x;
  if (idx >= BS_ * PPR) return;
  int row = idx / PPR, p = idx - row * PPR;
  int col = (p < 1024) ? (2 * p) : (2048 + 2 * (p - 1024));
  int d = p & 63;
  int s = row & (S_ - 1);
  float freq = expf(-(float)d * 0.14391156831212787f);  // ln(10000)/64
  float ang = (float)s * freq;
  float c = cosf(ang), sn = sinf(ang);
  unsigned short* ptr = qkv + (size_t)row * QKV_LD + col;
  float x1 = bf2f(ptr[0]), x2 = bf2f(ptr[1]);
  ptr[0] = f2bf(x1 * c - x2 * sn);
  ptr[1] = f2bf(x1 * sn + x2 * c);
}

// ---------------- V transpose: qkv V-cols -> vt[g][hd][s] ---------------------
__global__ __launch_bounds__(256)
void vtrans_kernel(const unsigned short* __restrict__ qkv,
                   unsigned short* __restrict__ vt) {
  __shared__ unsigned short tile[64 * 72];
  const int tid = threadIdx.x;
  const int s0 = blockIdx.x * 64;
  const int g = blockIdx.y >> 1;          // b*4 + kvh
  const int hh = (blockIdx.y & 1) * 64;
  const int b = g >> 2, kvh = g & 3;
#pragma unroll
  for (int i = 0; i < 2; ++i) {
    int chunk = tid + i * 256;
    int r = chunk >> 3, c = (chunk & 7) * 8;
    uint4 v = *(const uint4*)(qkv + (size_t)(b * S_ + s0 + r) * QKV_LD + 2560 + kvh * HD_ + hh + c);
    *(uint4*)(tile + r * 72 + c) = v;
  }
  __syncthreads();
#pragma unroll
  for (int i = 0; i < 2; ++i) {
    int chunk = tid + i * 256;
    int hdr = chunk >> 3, sc = (chunk & 7) * 8;
    union { unsigned short u[8]; uint4 v; } t;
#pragma unroll
    for (int j = 0; j < 8; ++j) t.u[j] = tile[(sc + j) * 72 + hdr];
    *(uint4*)(vt + (size_t)(g * HD_ + hh + hdr) * S_ + s0 + sc) = t.v;
  }
}

// ---------------- bf16 GEMM (m97-style): C = A[M][K] * BT[N][K]^T -------------
// BM=BN=128, BK=32; 256 threads = 4 waves 2x2; global_load_lds + XOR swizzle
template<bool OUT_BF16>
__global__ __launch_bounds__(256, 2)
void gemm_tn(const unsigned short* __restrict__ A,
             const unsigned short* __restrict__ BT,
             void* __restrict__ C, int M, int N, int K) {
  __shared__ unsigned short Ash[128 * 32];
  __shared__ unsigned short Bsh[128 * 32];
  const int tid = threadIdx.x;
  const int l = tid & 63;
  const int l16 = l & 15, l4 = l >> 4;
  const int wave = tid >> 6;
  const int wm = (wave >> 1) * 64, wn = (wave & 1) * 64;
  const int bm = blockIdx.y * 128, bn = blockIdx.x * 128;

  // staging map: chunk cc (16 rows), lane l -> row 16cc + (l>>2), colgroup g
  const int srow = l >> 2;
  const int sg = (((l & 3) - (l >> 4)) & 3) * 8;

  floatx4 acc[4][4] = {};

  for (int kb = 0; kb < K; kb += 32) {
    __syncthreads();
#pragma unroll
    for (int i = 0; i < 2; ++i) {
      int cc = wave + i * 4;
      async_cp16(A + (size_t)(bm + 16 * cc + srow) * K + kb + sg, &Ash[cc * 512]);
      async_cp16(BT + (size_t)(bn + 16 * cc + srow) * K + kb + sg, &Bsh[cc * 512]);
    }
    __syncthreads();
    bf16x8 af[4], bf[4];
#pragma unroll
    for (int t = 0; t < 4; ++t) {
      int row = wm + t * 16 + l16;
      int s = (l4 + (l16 >> 2)) & 3;
      af[t] = *(const bf16x8*)(Ash + row * 32 + s * 8);
    }
#pragma unroll
    for (int t = 0; t < 4; ++t) {
      int row = wn + t * 16 + l16;
      int s = (l4 + (l16 >> 2)) & 3;
      bf[t] = *(const bf16x8*)(Bsh + row * 32 + s * 8);
    }
#pragma unroll
    for (int tm = 0; tm < 4; ++tm)
#pragma unroll
      for (int tn = 0; tn < 4; ++tn)
        acc[tm][tn] = __builtin_amdgcn_mfma_f32_16x16x32_bf16(af[tm], bf[tn], acc[tm][tn], 0, 0, 0);
  }
#pragma unroll
  for (int tm = 0; tm < 4; ++tm)
#pragma unroll
    for (int tn = 0; tn < 4; ++tn)
#pragma unroll
      for (int r = 0; r < 4; ++r) {
        int row = bm + wm + tm * 16 + l4 * 4 + r;
        int col = bn + wn + tn * 16 + l16;
        float v = acc[tm][tn][r];
        if (OUT_BF16) ((unsigned short*)C)[(size_t)row * N + col] = f2bf(v);
        else          ((float*)C)[(size_t)row * N + col] = v;
      }
}

// ---------------- flash attention v3 (S^T trick, async dbuf, 2 blocks/CU) -----
// grid (64, 8): x = balanced q-tile pair, y = g = b*4+kvh
// block 256 = 4 waves = 4 heads; each phase handles 16 q-rows for all 4 heads.
__global__ __launch_bounds__(256, 2)
void gqa_attention(const unsigned short* __restrict__ qkv,
                   const unsigned short* __restrict__ vt,
                   unsigned short* __restrict__ out) {
  __shared__ unsigned short Ksh[2][32 * 128];  // swizzled: (row, s) holds g=(s-row)&15
  __shared__ unsigned short Vsh[2][128 * 32];  // swizzled: (row, s) holds g=(s-(row>>2))&3
  __shared__ unsigned short Psh[4][16 * 40];   // per-wave P^T stored [q][k], PST=40

  const int tid = threadIdx.x, l = tid & 63, wave = tid >> 6;
  const int l16 = l & 15, l4 = l >> 4;
  const int g = blockIdx.y, b = g >> 2, kvh = g & 3;
  const int h = kvh * 4 + wave;
  const int bx = blockIdx.x;

  // K staging map: chunk cc -> rows 4cc..4cc+3; lane l -> row 4cc+(l>>4), slot l&15
  const int k_subrow = l >> 4;
  // V staging map: chunk cc -> rows 16cc..16cc+15; lane l -> row 16cc+(l>>2), slot l&3
  const int v_subrow = l >> 2;
  const int v_g = (((l & 3) - (l >> 4)) & 3) * 8;

  for (int phase = 0; phase < 2; ++phase) {
    const int qt = phase ? (S_ - 16 - bx * 16) : (bx * 16);
    const int nch = ((qt + 15) >> 5) + 1;

    // Q as B-operand fragments: lane holds q = qt + l16, hd = c*32 + l4*8 + j
    bf16x8 qf[4];
    {
      const unsigned short* qp = qkv + (size_t)(b * S_ + qt + l16) * QKV_LD + h * HD_;
#pragma unroll
      for (int c = 0; c < 4; ++c)
        qf[c] = *(const bf16x8*)(qp + c * 32 + l4 * 8);
    }
    asm volatile("s_waitcnt vmcnt(0)" ::: "memory");

    // prologue: stage chunk 0 -> buf 0  (4 issues per wave)
    {
      const int kb = 0;
#pragma unroll
      for (int i = 0; i < 2; ++i) {
        int cc = wave + i * 4;
        int gk = (((l & 15) - 4 * cc - k_subrow) & 15) * 8;
        async_cp16(qkv + (size_t)(b * S_ + kb + 4 * cc + k_subrow) * QKV_LD + 2048 + kvh * HD_ + gk,
                   &Ksh[0][cc * 512]);
        async_cp16(vt + (size_t)(g * HD_ + 16 * cc + v_subrow) * S_ + kb + v_g,
                   &Vsh[0][cc * 512]);
      }
    }

    float m = -3e38f, lsum = 0.f;
    floatx4 acc[8] = {};

    for (int it = 0; it < nch; ++it) {
      const int kb = it * 32;
      const int cur = it & 1;
      // barrier A: all waves done reading buf[1-cur] from previous iter
      asm volatile("s_barrier" ::: "memory");
      // issue prefetch of chunk it+1 into buf[1-cur] (clamped to 0: benign)
      {
        const int kb2 = (it + 1 < nch) ? kb + 32 : 0;
#pragma unroll
        for (int i = 0; i < 2; ++i) {
          int cc = wave + i * 4;
          int gk = (((l & 15) - 4 * cc - k_subrow) & 15) * 8;
          async_cp16(qkv + (size_t)(b * S_ + kb2 + 4 * cc + k_subrow) * QKV_LD + 2048 + kvh * HD_ + gk,
                     &Ksh[cur ^ 1][cc * 512]);
          async_cp16(vt + (size_t)(g * HD_ + 16 * cc + v_subrow) * S_ + kb2 + v_g,
                     &Vsh[cur ^ 1][cc * 512]);
        }
      }
      // wait for our chunk-it loads (4 newer stay in flight), then sync landing
      asm volatile("s_waitcnt vmcnt(4)\n\ts_barrier" ::: "memory");

      // S^T = K * Q^T : rows = k-local (two halves), cols = q
      floatx4 sacc[2] = {};
#pragma unroll
      for (int half = 0; half < 2; ++half) {
        int krow = half * 16 + l16;
#pragma unroll
        for (int c = 0; c < 4; ++c) {
          int s = (c * 4 + l4 + l16) & 15;
          bf16x8 kf = *(const bf16x8*)(&Ksh[cur][krow * 128 + s * 8]);
          sacc[half] = __builtin_amdgcn_mfma_f32_16x16x32_bf16(kf, qf[c], sacc[half], 0, 0, 0);
        }
      }
      // scale + mask; per-lane: q = qt + l16 fixed, k = kb + half*16 + l4*4 + r
      float sv[8];
      const bool need_mask = (kb + 31 > qt);
#pragma unroll
      for (int half = 0; half < 2; ++half)
#pragma unroll
        for (int r = 0; r < 4; ++r) {
          float v = sacc[half][r] * SM_SCALE;
          if (need_mask) {
            int ka = kb + half * 16 + l4 * 4 + r;
            if (ka > qt + l16) v = -3e38f;
          }
          sv[half * 4 + r] = v;
        }
      // chunk max: local 8, then across l4 groups (lane bits 4,5)
      float mx = sv[0];
#pragma unroll
      for (int j = 1; j < 8; ++j) mx = fmaxf(mx, sv[j]);
      mx = fmaxf(mx, __shfl_xor(mx, 16, 64));
      mx = fmaxf(mx, __shfl_xor(mx, 32, 64));
      float mnew = fmaxf(m, mx);
      float alpha = __expf(m - mnew);
      // P = exp(s - mnew); pack into Psh[q][k] (2 x b64)
      float p[8], psum = 0.f;
#pragma unroll
      for (int j = 0; j < 8; ++j) { p[j] = __expf(sv[j] - mnew); psum += p[j]; }
      psum += __shfl_xor(psum, 16, 64);
      psum += __shfl_xor(psum, 32, 64);
      lsum = lsum * alpha + psum;
      m = mnew;
#pragma unroll
      for (int t = 0; t < 8; ++t)
#pragma unroll
        for (int r = 0; r < 4; ++r)
          acc[t][r] *= alpha;
#pragma unroll
      for (int half = 0; half < 2; ++half) {
        ushort4 pk;
        pk.x = f2bf(p[half * 4 + 0]); pk.y = f2bf(p[half * 4 + 1]);
        pk.z = f2bf(p[half * 4 + 2]); pk.w = f2bf(p[half * 4 + 3]);
        *(ushort4*)(&Psh[wave][l16 * 40 + half * 16 + l4 * 4]) = pk;
      }
      // O^T += V^T * P^T  (in-wave LDS RAW: DS pipe is in-order per wave)
      bf16x8 pf = *(const bf16x8*)(&Psh[wave][l16 * 40 + l4 * 8]);
#pragma unroll
      for (int t = 0; t < 8; ++t) {
        int row = t * 16 + l16;
        int s = (l4 + (l16 >> 2)) & 3;
        bf16x8 vf = *(const bf16x8*)(&Vsh[cur][row * 32 + s * 8]);
        acc[t] = __builtin_amdgcn_mfma_f32_16x16x32_bf16(vf, pf, acc[t], 0, 0, 0);
      }
    }
    // all waves done with LDS before next phase restages
    asm volatile("s_barrier" ::: "memory");

    // epilogue: lane q = qt + l16; acc[t][r] at hd = t*16 + l4*4 + r
    float inv = 1.0f / lsum;
    unsigned short* op = out + (size_t)(b * S_ + qt + l16) * 2048 + h * HD_;
#pragma unroll
    for (int t = 0; t < 8; ++t) {
      ushort4 o;
      o.x = f2bf(acc[t][0] * inv); o.y = f2bf(acc[t][1] * inv);
      o.z = f2bf(acc[t][2] * inv); o.w = f2bf(acc[t][3] * inv);
      *(ushort4*)(op + t * 16 + l4 * 4) = o;
    }
  }
}

// ---------------- launcher ----------------------------------------------------
extern "C" void kernel_launch(void* const* d_in, const int* in_sizes, int n_in,
                              void* d_out, int out_size, void* d_ws, size_t ws_size,
                              hipStream_t stream) {
  const float* x  = (const float*)d_in[0];
  const float* Wq = (const float*)d_in[1];
  const float* Wk = (const float*)d_in[2];
  const float* Wv = (const float*)d_in[3];
  const float* Wo = (const float*)d_in[4];
  float* out = (float*)d_out;

  char* ws = (char*)d_ws;
  unsigned short* xb    = (unsigned short*)(ws);                      // 16 MB (dead after GEMM1)
  unsigned short* wqkvT = (unsigned short*)(ws + 16777216);           // 12.6 MB: [3072][2048]
  unsigned short* woT   = (unsigned short*)(ws + 29360128);           // 8.4 MB: [2048][2048]
  unsigned short* qkv   = (unsigned short*)(ws + 37748736);           // 25.2 MB
  unsigned short* attn  = (unsigned short*)(ws + 62914560);           // 16.8 MB
  unsigned short* vt    = (unsigned short*)(ws);                      // 4.2 MB, aliases xb

  // x -> bf16
  cvt_bf16<<<(4096 * 2048 / 4 + 255) / 256, 256, 0, stream>>>(x, xb, 4096 * 2048 / 4);
  // weights -> bf16 transposed (W^T[N][K] row-major)
  cvt_bf16_t<<<dim3(32, 32), 256, 0, stream>>>(Wq, wqkvT, 2048, 2048, 0);
  cvt_bf16_t<<<dim3(8, 32),  256, 0, stream>>>(Wk, wqkvT, 512,  2048, 2048);
  cvt_bf16_t<<<dim3(8, 32),  256, 0, stream>>>(Wv, wqkvT, 512,  2048, 2560);
  cvt_bf16_t<<<dim3(32, 32), 256, 0, stream>>>(Wo, woT,  2048, 2048, 0);

  // qkv = x @ [Wq|Wk|Wv]
  gemm_tn<true><<<dim3(24, 32), 256, 0, stream>>>(xb, wqkvT, qkv, 4096, 3072, 2048);
  // RoPE in place on q,k
  rope_kernel<<<(4096 * 1280 + 255) / 256, 256, 0, stream>>>(qkv);
  // V transpose into vt[g][hd][s] (aliases xb, dead after GEMM1)
  vtrans_kernel<<<dim3(32, 16), 256, 0, stream>>>(qkv, vt);
  // flash attention
  gqa_attention<<<dim3(64, 8), 256, 0, stream>>>(qkv, vt, attn);
  // out = attn @ Wo
  gemm_tn<false><<<dim3(16, 32), 256, 0, stream>>>(attn, woT, out, 4096, 2048, 2048);
}

// Round 4
// 353.084 us; speedup vs baseline: 1.3902x; 1.0354x over previous
//
#include <hip/hip_runtime.h>
#include <hip/hip_bf16.h>
#include <cstdint>

#define B_ 2
#define S_ 2048
#define E_ 2048
#define H_ 16
#define KV_ 4
#define HD_ 128
#define BS_ (B_*S_)
#define QKV_LD 3072
#define SM_SCALE 0.08838834764831845f   // 1/sqrt(128)
#define SC_LOG2E 0.1275424488538497f    // SM_SCALE * log2(e)

typedef __attribute__((ext_vector_type(8))) __bf16 bf16x8;
typedef __attribute__((ext_vector_type(4))) float  floatx4;

__device__ __forceinline__ unsigned short f2bf(float f) {
  union { float f; unsigned u; } v; v.f = f;
  unsigned r = v.u + 0x7fffu + ((v.u >> 16) & 1u);   // RTNE
  return (unsigned short)(r >> 16);
}
__device__ __forceinline__ float bf2f(unsigned short u) {
  union { unsigned u; float f; } v; v.u = ((unsigned)u) << 16; return v.f;
}

__device__ __forceinline__ void async_cp16(const void* g, void* l) {
  __builtin_amdgcn_global_load_lds(
      (const __attribute__((address_space(1))) void*)g,
      (__attribute__((address_space(3))) void*)l, 16, 0, 0);
}

// ---------------- fp32 -> bf16 convert (plain) --------------------------------
__global__ __launch_bounds__(256)
void cvt_bf16(const float* __restrict__ src, unsigned short* __restrict__ dst,
              int n4) {
  int idx = blockIdx.x * 256 + threadIdx.x;
  if (idx >= n4) return;
  float4 v = *(const float4*)(src + (size_t)idx * 4);
  ushort4 o;
  o.x = f2bf(v.x); o.y = f2bf(v.y); o.z = f2bf(v.z); o.w = f2bf(v.w);
  *(ushort4*)(dst + (size_t)idx * 4) = o;
}

// ---------------- fp32 W[K][N] -> bf16 W^T[N][K] (transpose convert) ----------
__global__ __launch_bounds__(256)
void cvt_bf16_t(const float* __restrict__ src, unsigned short* __restrict__ dst,
                int N, int dld, int noff) {
  __shared__ float tile[64 * 65];
  const int t = threadIdx.x;
  const int bk = blockIdx.y * 64, bn = blockIdx.x * 64;
  const int r = t >> 2, cg = t & 3;
#pragma unroll
  for (int i = 0; i < 4; ++i) {
    int c = cg * 16 + i * 4;
    float4 v = *(const float4*)(src + (size_t)(bk + r) * N + bn + c);
    tile[r * 65 + c] = v.x; tile[r * 65 + c + 1] = v.y;
    tile[r * 65 + c + 2] = v.z; tile[r * 65 + c + 3] = v.w;
  }
  __syncthreads();
  const int nl = t >> 2, kg = t & 3;
  union { unsigned short u[16]; uint4 q[2]; } o;
#pragma unroll
  for (int j = 0; j < 16; ++j)
    o.u[j] = f2bf(tile[(kg * 16 + j) * 65 + nl]);
  unsigned short* dp = dst + (size_t)(noff + bn + nl) * dld + bk + kg * 16;
  *(uint4*)(dp) = o.q[0];
  *(uint4*)(dp + 8) = o.q[1];
}

// ---------------- RoPE on q (cols 0..2047) and k (cols 2048..2559) ------------
__global__ __launch_bounds__(256)
void rope_kernel(unsigned short* __restrict__ qkv) {
  const int PPR = 1280;
  int idx = blockIdx.x * 256 + threadIdx.x;
  if (idx >= BS_ * PPR) return;
  int row = idx / PPR, p = idx - row * PPR;
  int col = (p < 1024) ? (2 * p) : (2048 + 2 * (p - 1024));
  int d = p & 63;
  int s = row & (S_ - 1);
  float freq = expf(-(float)d * 0.14391156831212787f);
  float ang = (float)s * freq;
  float c = cosf(ang), sn = sinf(ang);
  unsigned short* ptr = qkv + (size_t)row * QKV_LD + col;
  float x1 = bf2f(ptr[0]), x2 = bf2f(ptr[1]);
  ptr[0] = f2bf(x1 * c - x2 * sn);
  ptr[1] = f2bf(x1 * sn + x2 * c);
}

// ---------------- V transpose: qkv V-cols -> vt[g][hd][s] ---------------------
__global__ __launch_bounds__(256)
void vtrans_kernel(const unsigned short* __restrict__ qkv,
                   unsigned short* __restrict__ vt) {
  __shared__ unsigned short tile[64 * 72];
  const int tid = threadIdx.x;
  const int s0 = blockIdx.x * 64;
  const int g = blockIdx.y >> 1;
  const int hh = (blockIdx.y & 1) * 64;
  const int b = g >> 2, kvh = g & 3;
#pragma unroll
  for (int i = 0; i < 2; ++i) {
    int chunk = tid + i * 256;
    int r = chunk >> 3, c = (chunk & 7) * 8;
    uint4 v = *(const uint4*)(qkv + (size_t)(b * S_ + s0 + r) * QKV_LD + 2560 + kvh * HD_ + hh + c);
    *(uint4*)(tile + r * 72 + c) = v;
  }
  __syncthreads();
#pragma unroll
  for (int i = 0; i < 2; ++i) {
    int chunk = tid + i * 256;
    int hdr = chunk >> 3, sc = (chunk & 7) * 8;
    union { unsigned short u[8]; uint4 v; } t;
#pragma unroll
    for (int j = 0; j < 8; ++j) t.u[j] = tile[(sc + j) * 72 + hdr];
    *(uint4*)(vt + (size_t)(g * HD_ + hh + hdr) * S_ + s0 + sc) = t.v;
  }
}

// ---------------- bf16 GEMM (m97-style): C = A[M][K] * BT[N][K]^T -------------
template<bool OUT_BF16>
__global__ __launch_bounds__(256, 2)
void gemm_tn(const unsigned short* __restrict__ A,
             const unsigned short* __restrict__ BT,
             void* __restrict__ C, int M, int N, int K) {
  __shared__ unsigned short Ash[128 * 32];
  __shared__ unsigned short Bsh[128 * 32];
  const int tid = threadIdx.x;
  const int l = tid & 63;
  const int l16 = l & 15, l4 = l >> 4;
  const int wave = tid >> 6;
  const int wm = (wave >> 1) * 64, wn = (wave & 1) * 64;
  const int bm = blockIdx.y * 128, bn = blockIdx.x * 128;

  const int srow = l >> 2;
  const int sg = (((l & 3) - (l >> 4)) & 3) * 8;

  floatx4 acc[4][4] = {};

  for (int kb = 0; kb < K; kb += 32) {
    __syncthreads();
#pragma unroll
    for (int i = 0; i < 2; ++i) {
      int cc = wave + i * 4;
      async_cp16(A + (size_t)(bm + 16 * cc + srow) * K + kb + sg, &Ash[cc * 512]);
      async_cp16(BT + (size_t)(bn + 16 * cc + srow) * K + kb + sg, &Bsh[cc * 512]);
    }
    __syncthreads();
    bf16x8 af[4], bf[4];
#pragma unroll
    for (int t = 0; t < 4; ++t) {
      int row = wm + t * 16 + l16;
      int s = (l4 + (l16 >> 2)) & 3;
      af[t] = *(const bf16x8*)(Ash + row * 32 + s * 8);
    }
#pragma unroll
    for (int t = 0; t < 4; ++t) {
      int row = wn + t * 16 + l16;
      int s = (l4 + (l16 >> 2)) & 3;
      bf[t] = *(const bf16x8*)(Bsh + row * 32 + s * 8);
    }
#pragma unroll
    for (int tm = 0; tm < 4; ++tm)
#pragma unroll
      for (int tn = 0; tn < 4; ++tn)
        acc[tm][tn] = __builtin_amdgcn_mfma_f32_16x16x32_bf16(af[tm], bf[tn], acc[tm][tn], 0, 0, 0);
  }
#pragma unroll
  for (int tm = 0; tm < 4; ++tm)
#pragma unroll
    for (int tn = 0; tn < 4; ++tn)
#pragma unroll
      for (int r = 0; r < 4; ++r) {
        int row = bm + wm + tm * 16 + l4 * 4 + r;
        int col = bn + wn + tn * 16 + l16;
        float v = acc[tm][tn][r];
        if (OUT_BF16) ((unsigned short*)C)[(size_t)row * N + col] = f2bf(v);
        else          ((float*)C)[(size_t)row * N + col] = v;
      }
}

// ---------------- flash attention v4 ------------------------------------------
// grid (8, 128): x = g (XCD-pinned: id%8 == g), y -> qt = 2032 - 16*y (big first)
// block 256 = 4 waves = 4 heads of group g; one 16-row q-tile per block.
__global__ __launch_bounds__(256, 2)
void gqa_attention(const unsigned short* __restrict__ qkv,
                   const unsigned short* __restrict__ vt,
                   unsigned short* __restrict__ out) {
  __shared__ unsigned short Ksh[2][32 * 128];  // swizzled: (row, s) holds colgroup (s-row)&15
  __shared__ unsigned short Vsh[2][128 * 32];  // swizzled
  __shared__ unsigned short Psh[4][16 * 40];   // per-wave P^T [q][k]

  const int tid = threadIdx.x, l = tid & 63, wave = tid >> 6;
  const int l16 = l & 15, l4 = l >> 4;
  const int g = blockIdx.x, b = g >> 2, kvh = g & 3;
  const int h = kvh * 4 + wave;
  const int qt = S_ - 16 - blockIdx.y * 16;     // largest first
  const int nch = (qt >> 5) + 1;

  const int k_subrow = l >> 4;
  const int v_subrow = l >> 2;
  const int v_g = (((l & 3) - (l >> 4)) & 3) * 8;

  // Q as B-operand fragments: lane holds q = qt + l16, hd = c*32 + l4*8 + j
  bf16x8 qf[4];
  {
    const unsigned short* qp = qkv + (size_t)(b * S_ + qt + l16) * QKV_LD + h * HD_;
#pragma unroll
    for (int c = 0; c < 4; ++c)
      qf[c] = *(const bf16x8*)(qp + c * 32 + l4 * 8);
  }
  asm volatile("s_waitcnt vmcnt(0)" ::: "memory");

  // prologue: stage chunk 0 -> buf 0
#pragma unroll
  for (int i = 0; i < 2; ++i) {
    int cc = wave + i * 4;
    int gk = (((l & 15) - 4 * cc - k_subrow) & 15) * 8;
    async_cp16(qkv + (size_t)(b * S_ + 4 * cc + k_subrow) * QKV_LD + 2048 + kvh * HD_ + gk,
               &Ksh[0][cc * 512]);
    async_cp16(vt + (size_t)(g * HD_ + 16 * cc + v_subrow) * S_ + v_g,
               &Vsh[0][cc * 512]);
  }

  float m = -3e38f, lsum = 0.f;
  floatx4 acc[8] = {};

  for (int it = 0; it < nch; ++it) {
    const int kb = it * 32;
    const int cur = it & 1;
    asm volatile("s_barrier" ::: "memory");  // all waves done reading buf[1-cur]
    {
      const int kb2 = (it + 1 < nch) ? kb + 32 : 0;
#pragma unroll
      for (int i = 0; i < 2; ++i) {
        int cc = wave + i * 4;
        int gk = (((l & 15) - 4 * cc - k_subrow) & 15) * 8;
        async_cp16(qkv + (size_t)(b * S_ + kb2 + 4 * cc + k_subrow) * QKV_LD + 2048 + kvh * HD_ + gk,
                   &Ksh[cur ^ 1][cc * 512]);
        async_cp16(vt + (size_t)(g * HD_ + 16 * cc + v_subrow) * S_ + kb2 + v_g,
                   &Vsh[cur ^ 1][cc * 512]);
      }
    }
    asm volatile("s_waitcnt vmcnt(4)\n\ts_barrier" ::: "memory");

    // S^T = K * Q^T
    floatx4 sacc[2] = {};
#pragma unroll
    for (int half = 0; half < 2; ++half) {
      int krow = half * 16 + l16;
#pragma unroll
      for (int c = 0; c < 4; ++c) {
        int s = (c * 4 + l4 + l16) & 15;
        bf16x8 kf = *(const bf16x8*)(&Ksh[cur][krow * 128 + s * 8]);
        sacc[half] = __builtin_amdgcn_mfma_f32_16x16x32_bf16(kf, qf[c], sacc[half], 0, 0, 0);
      }
    }
    // scale (log2e-folded) + mask
    float sv[8];
    const bool need_mask = (kb + 31 > qt);
#pragma unroll
    for (int half = 0; half < 2; ++half)
#pragma unroll
      for (int r = 0; r < 4; ++r) {
        float v = sacc[half][r] * SC_LOG2E;
        if (need_mask) {
          int ka = kb + half * 16 + l4 * 4 + r;
          if (ka > qt + l16) v = -3e38f;
        }
        sv[half * 4 + r] = v;
      }
    float mx = sv[0];
#pragma unroll
    for (int j = 1; j < 8; ++j) mx = fmaxf(mx, sv[j]);
    mx = fmaxf(mx, __shfl_xor(mx, 16, 64));
    mx = fmaxf(mx, __shfl_xor(mx, 32, 64));
    float mnew = fmaxf(m, mx);
    float p[8], psum = 0.f;
#pragma unroll
    for (int j = 0; j < 8; ++j) { p[j] = exp2f(sv[j] - mnew); psum += p[j]; }
    psum += __shfl_xor(psum, 16, 64);
    psum += __shfl_xor(psum, 32, 64);
    if (__any(mnew != m)) {            // wave-uniform: rescale only on max update
      float alpha = exp2f(m - mnew);
      lsum = lsum * alpha;
#pragma unroll
      for (int t = 0; t < 8; ++t)
#pragma unroll
        for (int r = 0; r < 4; ++r)
          acc[t][r] *= alpha;
      m = mnew;
    }
    lsum += psum;
#pragma unroll
    for (int half = 0; half < 2; ++half) {
      ushort4 pk;
      pk.x = f2bf(p[half * 4 + 0]); pk.y = f2bf(p[half * 4 + 1]);
      pk.z = f2bf(p[half * 4 + 2]); pk.w = f2bf(p[half * 4 + 3]);
      *(ushort4*)(&Psh[wave][l16 * 40 + half * 16 + l4 * 4]) = pk;
    }
    // O^T += V^T * P^T (in-wave LDS RAW: DS pipe in-order per wave)
    bf16x8 pf = *(const bf16x8*)(&Psh[wave][l16 * 40 + l4 * 8]);
#pragma unroll
    for (int t = 0; t < 8; ++t) {
      int row = t * 16 + l16;
      int s = (l4 + (l16 >> 2)) & 3;
      bf16x8 vf = *(const bf16x8*)(&Vsh[cur][row * 32 + s * 8]);
      acc[t] = __builtin_amdgcn_mfma_f32_16x16x32_bf16(vf, pf, acc[t], 0, 0, 0);
    }
  }

  // epilogue: lane q = qt + l16; acc[t][r] at hd = t*16 + l4*4 + r
  float inv = 1.0f / lsum;
  unsigned short* op = out + (size_t)(b * S_ + qt + l16) * 2048 + h * HD_;
#pragma unroll
  for (int t = 0; t < 8; ++t) {
    ushort4 o;
    o.x = f2bf(acc[t][0] * inv); o.y = f2bf(acc[t][1] * inv);
    o.z = f2bf(acc[t][2] * inv); o.w = f2bf(acc[t][3] * inv);
    *(ushort4*)(op + t * 16 + l4 * 4) = o;
  }
}

// ---------------- launcher ----------------------------------------------------
extern "C" void kernel_launch(void* const* d_in, const int* in_sizes, int n_in,
                              void* d_out, int out_size, void* d_ws, size_t ws_size,
                              hipStream_t stream) {
  const float* x  = (const float*)d_in[0];
  const float* Wq = (const float*)d_in[1];
  const float* Wk = (const float*)d_in[2];
  const float* Wv = (const float*)d_in[3];
  const float* Wo = (const float*)d_in[4];
  float* out = (float*)d_out;

  char* ws = (char*)d_ws;
  unsigned short* xb    = (unsigned short*)(ws);
  unsigned short* wqkvT = (unsigned short*)(ws + 16777216);
  unsigned short* woT   = (unsigned short*)(ws + 29360128);
  unsigned short* qkv   = (unsigned short*)(ws + 37748736);
  unsigned short* attn  = (unsigned short*)(ws + 62914560);
  unsigned short* vt    = (unsigned short*)(ws);             // aliases xb (dead after GEMM1)

  cvt_bf16<<<(4096 * 2048 / 4 + 255) / 256, 256, 0, stream>>>(x, xb, 4096 * 2048 / 4);
  cvt_bf16_t<<<dim3(32, 32), 256, 0, stream>>>(Wq, wqkvT, 2048, 2048, 0);
  cvt_bf16_t<<<dim3(8, 32),  256, 0, stream>>>(Wk, wqkvT, 512,  2048, 2048);
  cvt_bf16_t<<<dim3(8, 32),  256, 0, stream>>>(Wv, wqkvT, 512,  2048, 2560);
  cvt_bf16_t<<<dim3(32, 32), 256, 0, stream>>>(Wo, woT,  2048, 2048, 0);

  gemm_tn<true><<<dim3(24, 32), 256, 0, stream>>>(xb, wqkvT, qkv, 4096, 3072, 2048);
  rope_kernel<<<(4096 * 1280 + 255) / 256, 256, 0, stream>>>(qkv);
  vtrans_kernel<<<dim3(32, 16), 256, 0, stream>>>(qkv, vt);
  gqa_attention<<<dim3(8, 128), 256, 0, stream>>>(qkv, vt, attn);
  gemm_tn<false><<<dim3(16, 32), 256, 0, stream>>>(attn, woT, out, 4096, 2048, 2048);
}